// Round 11
// baseline (1578.289 us; speedup 1.0000x reference)
//
#include <hip/hip_runtime.h>
#include <hip/hip_fp16.h>
#include <math.h>

#define Bsz 128
#define Tsz 512
#define Hsz 1024
#define MS  128
#define NT  768

// ws layout: [64KB, +1.09MB) WBr: fp16 pairs p=1..35, TID-INTERLEAVED for the
// 512 matvec threads (R7 layout):
//   per pair, half offset o = k*4096 + tid*8 + e  (k=0..3, tid=0..511, e=0..7)
//   holds W(r,c)[tid>>2][(tid&3)*32 + (((k+(tid&3))&3)<<3) + e]
// -> LDS copies & reads: 64 consecutive 16B lanes per instr, 0 bank conflicts.
// -> global streams: 1KB contiguous per wave instruction, perfect coalescing.
// pair index p = c*(c+1)/2 + r  (block (r,c), r<=c)

// ---------------------------------------------------------------------------
__global__ __launch_bounds__(256)
void retile_whh(const float* __restrict__ W, __half* __restrict__ WBr) {
    const int p = blockIdx.x + 1;
    const int t = threadIdx.x;
    int c = 0;
    while ((c+1)*(c+2)/2 <= p) ++c;
    const int r = p - c*(c+1)/2;
    __half* wb = WBr + (size_t)(p-1) * MS * MS;
    for (int o = t; o < MS*MS; o += 256) {
        const int k  = o >> 12;
        const int tt = (o >> 3) & 511;
        const int e  = o & 7;
        const int row = tt >> 2, jq = tt & 3;
        const int col = jq*32 + (((k + jq) & 3) << 3) + e;
        wb[o] = __float2half(W[(size_t)(r*MS+row)*Hsz + c*MS + col]);
    }
}

__device__ __forceinline__ float fast_tanh(float x) {
    const float e = __expf(2.0f * x);
    return 1.0f - 2.0f * __builtin_amdgcn_rcpf(e + 1.0f);
}

template <int CTRL>
__device__ __forceinline__ float dpp_get(float v) {
    union { float f; int i; } u, o;
    u.f = v;
    o.i = __builtin_amdgcn_update_dpp(0, u.i, CTRL, 0xf, 0xf, true);
    return o.f;
}

// packed fp32 dual-FMA (VOP3P): acc.xy += a.xy * b.xy
__device__ __forceinline__ void pk_fma(float2& acc, float2 a, float2 b) {
    asm("v_pk_fma_f32 %0, %1, %2, %0" : "+v"(acc) : "v"(a), "v"(b));
}

union H4 { short4 s4; __half2 h2[2]; };
union F4 { float4 v; float2 h[2]; };

// ---------------------------------------------------------------------------
// Persistent Clockwork RNN, grid=128, block=768 (12 waves). ONE barrier/step.
// R10 base (886us; VGPR 124, conflicts 0, no spill) + WAVE SPECIALIZATION:
//   waves 0-7  (tid<512): do_cols (odd regions) + module0 (every region) —
//              code and layouts byte-identical to R10's verified paths.
//   waves 8-11 (tid>=512): even-region row updates (4 strided passes over
//              rows 128..1023) + per-step finalize (tid 704).
// Even regions: module0 and row updates now run CONCURRENTLY on different
// waves; 3 waves/SIMD in different phases cover each other's tanh/DPP/LDS
// stalls (R10 had 2 lockstep waves/SIMD). No math/layout changes.
// Register budget: 12 waves = 3/SIMD -> compiler budget ~170 >= 124 live.
// Tripwire: WRITE_SIZE ballooning means the budget theory failed (spills).
// (R9 lesson: h stays fp32 everywhere; weights fp16 are fine.)
// ---------------------------------------------------------------------------
__global__ __launch_bounds__(NT)
void cwrnn_kernel(const float* __restrict__ x,      // [B, T+1, 2, 1]
                  const float* __restrict__ W_ih,   // [H, 2]
                  const float* __restrict__ fc_w,   // [2, H]
                  const float* __restrict__ fc_b,   // [2]
                  const float* __restrict__ enc_w,  // [H, 2]
                  const float* __restrict__ Whh,    // [H, H] fp32 originals
                  const __half* __restrict__ WBr,   // fp16 pairs, interleaved
                  float* __restrict__ out)          // [B, T, 2]
{
    __shared__ __half  WL[3*MS*MS];     // (1,1),(1,2),(2,2): 96 KB, interleaved
    __shared__ float   Sp2s[36][MS];    // full row-sums, pairs r>=1 only
    __shared__ float   h_s[Hsz];        // cols 1..7 (col 0 lives in H0)
    __shared__ float   H0[2][MS];       // module-0 state, ping-pong
    __shared__ float2  x_s[Tsz+1];
    __shared__ float2  wih_s[Hsz];
    __shared__ float2  fcw_s[Hsz];
    __shared__ float2  OpM0[2][8];      // module-0 fc partials (dbuf, waves 0-7)
    __shared__ float2  OpHi[16];        // promoted hi-module fc partials
    __shared__ float2  OpHiN[16];       // staging (written by waves 8-11)
    __shared__ float   out_s[Tsz*2];    // staged outputs (bulk store at end)

    const int tid   = threadIdx.x;
    const int lane  = tid & 63;
    const int wave  = tid >> 6;
    const int b     = blockIdx.x;
    const int row00 = tid >> 2;         // valid for tid<512 paths
    const int jc    = tid & 3;

    const float2* xb = (const float2*)(x + (size_t)b*(Tsz+1)*2);
    float* outb = out + (size_t)b*Tsz*2;

    for (int i = tid; i < Tsz+1; i += NT) x_s[i] = xb[i];
    for (int i = tid; i < Hsz; i += NT) wih_s[i] = ((const float2*)W_ih)[i];
    for (int i = tid; i < Hsz; i += NT) fcw_s[i] = make_float2(fc_w[i], fc_w[Hsz+i]);
    // WL staging: pairs p=2 ((1,1)), p=4 ((1,2)), p=5 ((2,2)); linear int4 copy
    {
        const int PSEL[3] = {2, 4, 5};
        for (int i = tid; i < 3*MS*MS/8; i += NT) {
            const int pi = i >> 11, rem = i & 2047;
            ((int4*)WL)[i] =
                ((const int4*)(WBr + (size_t)(PSEL[pi]-1)*MS*MS))[rem];
        }
    }
    if (tid < 16) { OpHi[tid] = make_float2(0.f,0.f); OpHiN[tid] = make_float2(0.f,0.f); }
    const float fb0 = fc_b[0], fb1 = fc_b[1];

    // Weight register caches (matvec threads only)
    F4 w00[8];
    short4 w01[8], w02[8];
    if (tid < 512) {
        #pragma unroll
        for (int u = 0; u < 8; ++u) {
            const int uu = (u + 2*jc) & 7;
            w00[u].v = *(const float4*)(Whh + (size_t)row00*Hsz + jc*32 + uu*4);
        }
        #pragma unroll
        for (int k = 0; k < 4; ++k) {
            *(int4*)(&w01[2*k]) = *(const int4*)(WBr + (size_t)0*MS*MS + k*4096 + tid*8);
            *(int4*)(&w02[2*k]) = *(const int4*)(WBr + (size_t)2*MS*MS + k*4096 + tid*8);
        }
    }

    {   // h0 = x[:,0] @ enc_w.T
        const float2 x0 = xb[0];
        for (int i = tid; i < Hsz; i += NT) {
            const float2 ew = ((const float2*)enc_w)[i];
            const float v = x0.x*ew.x + x0.y*ew.y;
            h_s[i] = v;
            if (i < MS) H0[0][i] = v;
        }
    }
    __syncthreads();

    float R1=0.f,R2=0.f,R3=0.f,R4=0.f,R5=0.f,R6=0.f,R7=0.f;

    auto load_hq = [&](int c, F4* hq) {
        #pragma unroll
        for (int u = 0; u < 8; ++u) {
            const int uu = (u + 2*jc) & 7;
            hq[u].v = *(const float4*)(h_s + c*MS + jc*32 + uu*4);
        }
    };
    auto pair_acc16 = [&](const short4* w, const F4* hq) -> float {
        float2 a0 = {0.f,0.f}, a1 = {0.f,0.f};
        #pragma unroll
        for (int u = 0; u < 8; ++u) {
            H4 ww; ww.s4 = w[u];
            pk_fma(a0, __half22float2(ww.h2[0]), hq[u].h[0]);
            pk_fma(a1, __half22float2(ww.h2[1]), hq[u].h[1]);
        }
        return (a0.x + a0.y) + (a1.x + a1.y);
    };
    // conflict-free LDS pair read: 4 x ds_read_b128, lanes consecutive 16B
    auto wl_read = [&](int pi, short4* w) {
        const __half* base = WL + (size_t)pi*MS*MS + tid*8;
        #pragma unroll
        for (int k = 0; k < 4; ++k)
            *(int4*)(&w[2*k]) = *(const int4*)(base + k*4096);
    };
    // coalesced global pair read: 4 x dwordx4, 1KB contiguous per wave instr
    auto wg_load = [&](int p, short4* w) {
        const __half* base = WBr + (size_t)(p-1)*MS*MS + tid*8;
        #pragma unroll
        for (int k = 0; k < 4; ++k)
            *(int4*)(&w[2*k]) = *(const int4*)(base + k*4096);
    };

    // Refresh contributions of cols 1..ashad (matvec threads only):
    //  r=0 -> register quarter-partials Rc; r>=1 -> quad-reduced Sp2s
    auto do_cols = [&](int ashad) {
        F4 hq[8];
        short4 wA[8], wB[8];
        if (ashad >= 3) wg_load(6, wA);          // prefetch (0,3) early
        load_hq(1, hq);
        wl_read(0, wB);                          // (1,1)
        R1 = pair_acc16(w01, hq);
        { float aa = pair_acc16(wB, hq);
          aa += dpp_get<0xB1>(aa); aa += dpp_get<0x4E>(aa);
          if (jc == 0) Sp2s[2][row00] = aa; }            // (1,1)
        if (ashad >= 2) {
            load_hq(2, hq);
            R2 = pair_acc16(w02, hq);
            wl_read(1, wB);
            { float aa = pair_acc16(wB, hq);
              aa += dpp_get<0xB1>(aa); aa += dpp_get<0x4E>(aa);
              if (jc == 0) Sp2s[4][row00] = aa; }        // (1,2)
            wl_read(2, wB);
            { float aa = pair_acc16(wB, hq);
              aa += dpp_get<0xB1>(aa); aa += dpp_get<0x4E>(aa);
              if (jc == 0) Sp2s[5][row00] = aa; }        // (2,2)
        }
        if (ashad >= 3) {
            // streamed pipeline: (0,3),(1,3)...(ashad,ashad), depth-2 prefetch
            load_hq(3, hq);
            int cc = 3, rr = 0;
            while (true) {
                int rn = rr + 1, cn = cc;
                if (rn > cn) { cn += 1; rn = 0; }
                const bool hn = (cn <= ashad);
                if (hn) wg_load(cn*(cn+1)/2 + rn, wB);
                float aa = pair_acc16(wA, hq);
                if (rr == 0) {
                    switch (cc) {
                        case 3: R3 = aa; break;
                        case 4: R4 = aa; break;
                        case 5: R5 = aa; break;
                        case 6: R6 = aa; break;
                        default: R7 = aa; break;
                    }
                } else {
                    aa += dpp_get<0xB1>(aa); aa += dpp_get<0x4E>(aa);
                    if (jc == 0) Sp2s[cc*(cc+1)/2 + rr][row00] = aa;
                }
                if (!hn) break;
                if (cn != cc) load_hq(cn, hq);
                cc = cn; rr = rn;
                #pragma unroll
                for (int u = 0; u < 8; ++u) wA[u] = wB[u];
            }
        }
    };

    if (tid < 512) do_cols(7);  // init Sp2s + R1..R7 from encoder state
    __syncthreads();

    for (int t = 0; t < Tsz; ++t) {
        const int A  = (t == 0) ? 7 : ((t & 1) ? 0 : min(__ffs(t)-1, 7));
        const int ap = (t & 1) ? ((t == 1) ? 7 : min(__ffs(t-1)-1, 7)) : 0;
        const float2 xt = x_s[t+1];

        if (tid < 512) {
            // ---- deferred refresh of cols active at t-1 (odd regions) ----
            if (ap >= 1) do_cols(ap);

            // ---- module 0: inline diagonal + register off-diagonals ----
            const float* h0r = H0[t & 1];
            float2 a0 = {0.f,0.f}, a1 = {0.f,0.f};
            #pragma unroll
            for (int u = 0; u < 8; ++u) {
                const int uu = (u + 2*jc) & 7;
                F4 hv; hv.v = *(const float4*)(h0r + jc*32 + uu*4);
                pk_fma(a0, w00[u].h[0], hv.h[0]);
                pk_fma(a1, w00[u].h[1], hv.h[1]);
            }
            float a = (a0.x + a0.y) + (a1.x + a1.y);
            a += ((R1+R2)+(R3+R4)) + ((R5+R6)+R7);
            a += dpp_get<0xB1>(a); a += dpp_get<0x4E>(a);   // quad reduce
            const float2 wih0 = wih_s[row00];
            const float hv0 = fast_tanh(a + xt.x*wih0.x + xt.y*wih0.y);
            if (jc == 0) H0[(t+1)&1][row00] = hv0;
            const float2 fw0 = fcw_s[row00];
            float o0 = (jc == 0) ? hv0*fw0.x : 0.f;
            float o1 = (jc == 0) ? hv0*fw0.y : 0.f;
            o0 += dpp_get<0x111>(o0); o1 += dpp_get<0x111>(o1);
            o0 += dpp_get<0x112>(o0); o1 += dpp_get<0x112>(o1);
            o0 += dpp_get<0x114>(o0); o1 += dpp_get<0x114>(o1);
            o0 += dpp_get<0x118>(o0); o1 += dpp_get<0x118>(o1);
            o0 += dpp_get<0x142>(o0); o1 += dpp_get<0x142>(o1);
            o0 += dpp_get<0x143>(o0); o1 += dpp_get<0x143>(o1);
            if (lane == 63) OpM0[t&1][wave] = make_float2(o0, o1);
        } else {
            // ---- waves 8-11: row updates for modules 1..A (even & t==0) ----
            if (A >= 1) {
                const int nrows = (A+1)*MS;
                #pragma unroll
                for (int p = 0; p < 4; ++p) {
                    const int g = MS + (tid - 512) + p*256;
                    if (g < nrows) {
                        const int r = g >> 7, il = g & (MS-1);
                        float sc[8];
                        #pragma unroll
                        for (int c = 1; c < 8; ++c)
                            sc[c] = Sp2s[c*(c+1)/2 + ((c < r) ? c : r)][il];
                        const float2 wih2 = wih_s[g];
                        float pre = xt.x*wih2.x + xt.y*wih2.y;
                        #pragma unroll
                        for (int c = 1; c < 8; ++c) pre += (c >= r) ? sc[c] : 0.f;
                        const float hv = fast_tanh(pre);
                        h_s[g] = hv;
                        const float2 fw = fcw_s[g];
                        float o0 = hv*fw.x, o1 = hv*fw.y;
                        o0 += dpp_get<0x111>(o0); o1 += dpp_get<0x111>(o1);
                        o0 += dpp_get<0x112>(o0); o1 += dpp_get<0x112>(o1);
                        o0 += dpp_get<0x114>(o0); o1 += dpp_get<0x114>(o1);
                        o0 += dpp_get<0x118>(o0); o1 += dpp_get<0x118>(o1);
                        o0 += dpp_get<0x142>(o0); o1 += dpp_get<0x142>(o1);
                        o0 += dpp_get<0x143>(o0); o1 += dpp_get<0x143>(o1);
                        if (lane == 63)
                            OpHiN[2 + (wave - 8) + 4*p] = make_float2(o0, o1);
                    }
                }
            }
            // ---- finalize out[t-1] into out_s (LDS only) ----
            if (t > 0 && tid == 704) {
                const int tp = t - 1;
                if (ap >= 1) {
                    for (int k = 2; k <= 2*ap+1; ++k) OpHi[k] = OpHiN[k];
                }
                float o0 = fb0, o1 = fb1;
                #pragma unroll
                for (int w = 0; w < 8; ++w) { o0 += OpM0[tp&1][w].x; o1 += OpM0[tp&1][w].y; }
                #pragma unroll
                for (int k = 2; k < 16; ++k) { o0 += OpHi[k].x; o1 += OpHi[k].y; }
                out_s[2*tp]   = o0;
                out_s[2*tp+1] = o1;
            }
        }

        __syncthreads();            // the ONE barrier per step
    }

    if (tid == 704) {               // out[511]
        float o0 = fb0, o1 = fb1;
        #pragma unroll
        for (int w = 0; w < 8; ++w) { o0 += OpM0[1][w].x; o1 += OpM0[1][w].y; }
        #pragma unroll
        for (int k = 2; k < 16; ++k) { o0 += OpHi[k].x; o1 += OpHi[k].y; }
        out_s[2*(Tsz-1)]   = o0;
        out_s[2*(Tsz-1)+1] = o1;
    }
    __syncthreads();
    for (int i = tid; i < Tsz*2; i += NT) outb[i] = out_s[i];
}

// ---------------------------------------------------------------------------
extern "C" void kernel_launch(void* const* d_in, const int* in_sizes, int n_in,
                              void* d_out, int out_size, void* d_ws, size_t ws_size,
                              hipStream_t stream) {
    const float* x     = (const float*)d_in[0];
    const float* W_ih  = (const float*)d_in[1];
    const float* W_hh  = (const float*)d_in[2];
    const float* fc_w  = (const float*)d_in[3];
    const float* fc_b  = (const float*)d_in[4];
    const float* enc_w = (const float*)d_in[5];
    float* outp = (float*)d_out;
    __half* WBr = (__half*)((char*)d_ws + 65536);        // 35*16384*2 B

    retile_whh<<<35, 256, 0, stream>>>(W_hh, WBr);
    cwrnn_kernel<<<Bsz, NT, 0, stream>>>(x, W_ih, fc_w, fc_b, enc_w, W_hh, WBr, outp);
}

// Round 12
// 925.566 us; speedup vs baseline: 1.7052x; 1.7052x over previous
//
#include <hip/hip_runtime.h>
#include <hip/hip_fp16.h>
#include <math.h>

#define Bsz 128
#define Tsz 512
#define Hsz 1024
#define MS  128
#define NT  512

// ws layout: [64KB, +1.09MB) WBr: fp16 pairs p=1..35, TID-INTERLEAVED (R7):
//   per pair, half offset o = k*4096 + tid*8 + e  (k=0..3, tid=0..511, e=0..7)
//   holds W(r,c)[tid>>2][(tid&3)*32 + (((k+(tid&3))&3)<<3) + e]
// -> LDS copies & reads: 64 consecutive 16B lanes per instr, 0 bank conflicts.
// -> global streams: 1KB contiguous per wave instruction, perfect coalescing.
// pair index p = c*(c+1)/2 + r  (block (r,c), r<=c)

// ---------------------------------------------------------------------------
__global__ __launch_bounds__(256)
void retile_whh(const float* __restrict__ W, __half* __restrict__ WBr) {
    const int p = blockIdx.x + 1;
    const int t = threadIdx.x;
    int c = 0;
    while ((c+1)*(c+2)/2 <= p) ++c;
    const int r = p - c*(c+1)/2;
    __half* wb = WBr + (size_t)(p-1) * MS * MS;
    for (int o = t; o < MS*MS; o += 256) {
        const int k  = o >> 12;
        const int tt = (o >> 3) & 511;
        const int e  = o & 7;
        const int row = tt >> 2, jq = tt & 3;
        const int col = jq*32 + (((k + jq) & 3) << 3) + e;
        wb[o] = __float2half(W[(size_t)(r*MS+row)*Hsz + c*MS + col]);
    }
}

__device__ __forceinline__ float fast_tanh(float x) {
    const float e = __expf(2.0f * x);
    return 1.0f - 2.0f * __builtin_amdgcn_rcpf(e + 1.0f);
}

template <int CTRL>
__device__ __forceinline__ float dpp_get(float v) {
    union { float f; int i; } u, o;
    u.f = v;
    o.i = __builtin_amdgcn_update_dpp(0, u.i, CTRL, 0xf, 0xf, true);
    return o.f;
}

// packed fp32 dual-FMA (VOP3P): acc.xy += a.xy * b.xy
__device__ __forceinline__ void pk_fma(float2& acc, float2 a, float2 b) {
    asm("v_pk_fma_f32 %0, %1, %2, %0" : "+v"(acc) : "v"(a), "v"(b));
}

union H4 { short4 s4; __half2 h2[2]; };
union F4 { float4 v; float2 h[2]; };

// ---------------------------------------------------------------------------
// Persistent Clockwork RNN, grid=128, block=512 (8 waves). ONE barrier/step.
// HARD CONSTRAINT (R3/4/5/8/11): 512 threads -> 128-VGPR budget (768->84,
// 1024->64); live set must stay <=128 or scratch spills (WRITE_SIZE tell).
//
// R10 base (886us; VGPR 124, conflicts 0, WRITE 512KB) + do_cols PHASE SPLIT:
//   phase A (pre-module0): only the r=0 register/streamed pairs -> R1..R7
//     (module0's gate). Module0's input chain no longer waits for Sp2s work.
//   phase B (post-module0): all Sp2s pairs (WL (1,1),(1,2),(2,2) + streamed
//     r>=1) — consumed only NEXT region, so they issue into module0's
//     tanh/DPP stall shadow and drain before the barrier.
// Same sums, same layouts, same barrier structure — ordering only.
// (R9 lesson: h stays fp32 everywhere; weights fp16 are fine.)
// ---------------------------------------------------------------------------
__global__ __launch_bounds__(NT)
void cwrnn_kernel(const float* __restrict__ x,      // [B, T+1, 2, 1]
                  const float* __restrict__ W_ih,   // [H, 2]
                  const float* __restrict__ fc_w,   // [2, H]
                  const float* __restrict__ fc_b,   // [2]
                  const float* __restrict__ enc_w,  // [H, 2]
                  const float* __restrict__ Whh,    // [H, H] fp32 originals
                  const __half* __restrict__ WBr,   // fp16 pairs, interleaved
                  float* __restrict__ out)          // [B, T, 2]
{
    __shared__ __half  WL[3*MS*MS];     // (1,1),(1,2),(2,2): 96 KB, interleaved
    __shared__ float   Sp2s[36][MS];    // full row-sums, pairs r>=1 only
    __shared__ float   h_s[Hsz];        // cols 1..7 (col 0 lives in H0)
    __shared__ float   H0[2][MS];       // module-0 state, ping-pong
    __shared__ float2  x_s[Tsz+1];
    __shared__ float2  wih_s[Hsz];
    __shared__ float2  fcw_s[Hsz];
    __shared__ float2  OpM0[2][8];      // module-0 fc partials (dbuf)
    __shared__ float2  OpHi[16];        // promoted hi-module fc partials
    __shared__ float2  OpHiN[16];       // staging (written at even regions)
    __shared__ float   out_s[Tsz*2];    // staged outputs (bulk store at end)

    const int tid   = threadIdx.x;
    const int lane  = tid & 63;
    const int wave  = tid >> 6;
    const int b     = blockIdx.x;
    const int row00 = tid >> 2;
    const int jc    = tid & 3;

    const float2* xb = (const float2*)(x + (size_t)b*(Tsz+1)*2);
    float* outb = out + (size_t)b*Tsz*2;

    for (int i = tid; i < Tsz+1; i += NT) x_s[i] = xb[i];
    for (int i = tid; i < Hsz; i += NT) wih_s[i] = ((const float2*)W_ih)[i];
    for (int i = tid; i < Hsz; i += NT) fcw_s[i] = make_float2(fc_w[i], fc_w[Hsz+i]);
    // WL staging: pairs p=2 ((1,1)), p=4 ((1,2)), p=5 ((2,2)); linear int4 copy
    {
        const int PSEL[3] = {2, 4, 5};
        for (int i = tid; i < 3*MS*MS/8; i += NT) {
            const int pi = i >> 11, rem = i & 2047;
            ((int4*)WL)[i] =
                ((const int4*)(WBr + (size_t)(PSEL[pi]-1)*MS*MS))[rem];
        }
    }
    if (tid < 16) { OpHi[tid] = make_float2(0.f,0.f); OpHiN[tid] = make_float2(0.f,0.f); }
    const float fb0 = fc_b[0], fb1 = fc_b[1];

    // W00 fp32 register cache, rotated chunk order (matches hq layout)
    F4 w00[8];
    #pragma unroll
    for (int u = 0; u < 8; ++u) {
        const int uu = (u + 2*jc) & 7;
        w00[u].v = *(const float4*)(Whh + (size_t)row00*Hsz + jc*32 + uu*4);
    }
    // fp16 register pairs (0,1)=p1, (0,2)=p3 from interleaved WBr
    short4 w01[8], w02[8];
    #pragma unroll
    for (int k = 0; k < 4; ++k) {
        *(int4*)(&w01[2*k]) = *(const int4*)(WBr + (size_t)0*MS*MS + k*4096 + tid*8);
        *(int4*)(&w02[2*k]) = *(const int4*)(WBr + (size_t)2*MS*MS + k*4096 + tid*8);
    }

    {   // h0 = x[:,0] @ enc_w.T
        const float2 x0 = xb[0];
        for (int i = tid; i < Hsz; i += NT) {
            const float2 ew = ((const float2*)enc_w)[i];
            const float v = x0.x*ew.x + x0.y*ew.y;
            h_s[i] = v;
            if (i < MS) H0[0][i] = v;
        }
    }
    __syncthreads();

    float R1=0.f,R2=0.f,R3=0.f,R4=0.f,R5=0.f,R6=0.f,R7=0.f;

    auto load_hq = [&](int c, F4* hq) {
        #pragma unroll
        for (int u = 0; u < 8; ++u) {
            const int uu = (u + 2*jc) & 7;
            hq[u].v = *(const float4*)(h_s + c*MS + jc*32 + uu*4);
        }
    };
    auto pair_acc16 = [&](const short4* w, const F4* hq) -> float {
        float2 a0 = {0.f,0.f}, a1 = {0.f,0.f};
        #pragma unroll
        for (int u = 0; u < 8; ++u) {
            H4 ww; ww.s4 = w[u];
            pk_fma(a0, __half22float2(ww.h2[0]), hq[u].h[0]);
            pk_fma(a1, __half22float2(ww.h2[1]), hq[u].h[1]);
        }
        return (a0.x + a0.y) + (a1.x + a1.y);
    };
    // conflict-free LDS pair read: 4 x ds_read_b128, lanes consecutive 16B
    auto wl_read = [&](int pi, short4* w) {
        const __half* base = WL + (size_t)pi*MS*MS + tid*8;
        #pragma unroll
        for (int k = 0; k < 4; ++k)
            *(int4*)(&w[2*k]) = *(const int4*)(base + k*4096);
    };
    // coalesced global pair read: 4 x dwordx4, 1KB contiguous per wave instr
    auto wg_load = [&](int p, short4* w) {
        const __half* base = WBr + (size_t)(p-1)*MS*MS + tid*8;
        #pragma unroll
        for (int k = 0; k < 4; ++k)
            *(int4*)(&w[2*k]) = *(const int4*)(base + k*4096);
    };

    // phase A: r=0 pairs only -> register quarter-partials R1..Rashad
    // (the module-0 gate; no Sp2s writes, no DPP)
    auto do_cols_A = [&](int ashad) {
        F4 hq[8];
        short4 wA[8], wB[8];
        if (ashad >= 3) wg_load(6, wA);          // prefetch (0,3) early
        load_hq(1, hq);
        R1 = pair_acc16(w01, hq);
        if (ashad >= 2) { load_hq(2, hq); R2 = pair_acc16(w02, hq); }
        if (ashad >= 3) {
            for (int c = 3; c <= ashad; ++c) {   // stream (0,3)..(0,ashad)
                if (c < ashad) wg_load((c+1)*(c+2)/2, wB);
                load_hq(c, hq);
                const float aa = pair_acc16(wA, hq);
                switch (c) {
                    case 3: R3 = aa; break;
                    case 4: R4 = aa; break;
                    case 5: R5 = aa; break;
                    case 6: R6 = aa; break;
                    default: R7 = aa; break;
                }
                #pragma unroll
                for (int u = 0; u < 8; ++u) wA[u] = wB[u];
            }
        }
    };

    // phase B: all r>=1 pairs -> quad-reduced Sp2s (consumed next region;
    // runs after module0, fills its stall shadow)
    auto do_cols_B = [&](int ashad) {
        F4 hq[8];
        short4 wA[8], wB[8];
        if (ashad >= 3) wg_load(7, wA);          // prefetch (1,3) early
        load_hq(1, hq);
        wl_read(0, wB);                          // (1,1)
        { float aa = pair_acc16(wB, hq);
          aa += dpp_get<0xB1>(aa); aa += dpp_get<0x4E>(aa);
          if (jc == 0) Sp2s[2][row00] = aa; }
        if (ashad >= 2) {
            load_hq(2, hq);
            wl_read(1, wB);
            { float aa = pair_acc16(wB, hq);
              aa += dpp_get<0xB1>(aa); aa += dpp_get<0x4E>(aa);
              if (jc == 0) Sp2s[4][row00] = aa; }        // (1,2)
            wl_read(2, wB);
            { float aa = pair_acc16(wB, hq);
              aa += dpp_get<0xB1>(aa); aa += dpp_get<0x4E>(aa);
              if (jc == 0) Sp2s[5][row00] = aa; }        // (2,2)
        }
        if (ashad >= 3) {
            // streamed r>=1 pairs: (1,3),(2,3),(3,3),(1,4)... depth-2 prefetch
            load_hq(3, hq);
            int cc = 3, rr = 1;
            while (true) {
                int rn = rr + 1, cn = cc;
                if (rn > cn) { cn += 1; rn = 1; }
                const bool hn = (cn <= ashad);
                if (hn) wg_load(cn*(cn+1)/2 + rn, wB);
                float aa = pair_acc16(wA, hq);
                aa += dpp_get<0xB1>(aa); aa += dpp_get<0x4E>(aa);
                if (jc == 0) Sp2s[cc*(cc+1)/2 + rr][row00] = aa;
                if (!hn) break;
                if (cn != cc) load_hq(cn, hq);
                cc = cn; rr = rn;
                #pragma unroll
                for (int u = 0; u < 8; ++u) wA[u] = wB[u];
            }
        }
    };

    do_cols_A(7);               // init R1..R7 + Sp2s from encoder state
    do_cols_B(7);
    __syncthreads();

    for (int t = 0; t < Tsz; ++t) {
        const int A  = (t == 0) ? 7 : ((t & 1) ? 0 : min(__ffs(t)-1, 7));
        const int ap = (t & 1) ? ((t == 1) ? 7 : min(__ffs(t-1)-1, 7)) : 0;
        const float2 xt = x_s[t+1];

        // ---- phase A: R-partials for cols active at t-1 (odd regions) ----
        if (ap >= 1) do_cols_A(ap);

        // ---- module 0: inline diagonal + register off-diagonals ----
        {
            const float* h0r = H0[t & 1];
            float2 a0 = {0.f,0.f}, a1 = {0.f,0.f};
            #pragma unroll
            for (int u = 0; u < 8; ++u) {
                const int uu = (u + 2*jc) & 7;
                F4 hv; hv.v = *(const float4*)(h0r + jc*32 + uu*4);
                pk_fma(a0, w00[u].h[0], hv.h[0]);
                pk_fma(a1, w00[u].h[1], hv.h[1]);
            }
            float a = (a0.x + a0.y) + (a1.x + a1.y);
            a += ((R1+R2)+(R3+R4)) + ((R5+R6)+R7);
            a += dpp_get<0xB1>(a); a += dpp_get<0x4E>(a);   // quad reduce
            const float2 wih0 = wih_s[row00];
            const float hv0 = fast_tanh(a + xt.x*wih0.x + xt.y*wih0.y);
            if (jc == 0) H0[(t+1)&1][row00] = hv0;
            const float2 fw0 = fcw_s[row00];
            float o0 = (jc == 0) ? hv0*fw0.x : 0.f;
            float o1 = (jc == 0) ? hv0*fw0.y : 0.f;
            o0 += dpp_get<0x111>(o0); o1 += dpp_get<0x111>(o1);
            o0 += dpp_get<0x112>(o0); o1 += dpp_get<0x112>(o1);
            o0 += dpp_get<0x114>(o0); o1 += dpp_get<0x114>(o1);
            o0 += dpp_get<0x118>(o0); o1 += dpp_get<0x118>(o1);
            o0 += dpp_get<0x142>(o0); o1 += dpp_get<0x142>(o1);
            o0 += dpp_get<0x143>(o0); o1 += dpp_get<0x143>(o1);
            if (lane == 63) OpM0[t&1][wave] = make_float2(o0, o1);
        }

        // ---- phase B: Sp2s pairs (consumed next region) in the shadow ----
        if (ap >= 1) do_cols_B(ap);

        // ---- modules 1..A: row updates from Sp2s (even & t==0) ----
        if (A >= 1) {
            const int nrows = (A+1)*MS;
            {
                const int g = MS + tid;
                if (g < nrows) {
                    const int r = g >> 7, il = g & (MS-1);
                    float sc[8];
                    #pragma unroll
                    for (int c = 1; c < 8; ++c)
                        sc[c] = Sp2s[c*(c+1)/2 + ((c < r) ? c : r)][il];
                    const float2 wih2 = wih_s[g];
                    float pre = xt.x*wih2.x + xt.y*wih2.y;
                    #pragma unroll
                    for (int c = 1; c < 8; ++c) pre += (c >= r) ? sc[c] : 0.f;
                    const float hv = fast_tanh(pre);
                    h_s[g] = hv;
                    const float2 fw = fcw_s[g];
                    float o0 = hv*fw.x, o1 = hv*fw.y;
                    o0 += dpp_get<0x111>(o0); o1 += dpp_get<0x111>(o1);
                    o0 += dpp_get<0x112>(o0); o1 += dpp_get<0x112>(o1);
                    o0 += dpp_get<0x114>(o0); o1 += dpp_get<0x114>(o1);
                    o0 += dpp_get<0x118>(o0); o1 += dpp_get<0x118>(o1);
                    o0 += dpp_get<0x142>(o0); o1 += dpp_get<0x142>(o1);
                    o0 += dpp_get<0x143>(o0); o1 += dpp_get<0x143>(o1);
                    if (lane == 63) OpHiN[2 + wave] = make_float2(o0, o1);
                }
            }
            {
                const int g = 5*MS + tid;
                if (g < nrows) {
                    const int r = g >> 7, il = g & (MS-1);
                    float sc[8];
                    #pragma unroll
                    for (int c = 1; c < 8; ++c)
                        sc[c] = Sp2s[c*(c+1)/2 + ((c < r) ? c : r)][il];
                    const float2 wih2 = wih_s[g];
                    float pre = xt.x*wih2.x + xt.y*wih2.y;
                    #pragma unroll
                    for (int c = 1; c < 8; ++c) pre += (c >= r) ? sc[c] : 0.f;
                    const float hv = fast_tanh(pre);
                    h_s[g] = hv;
                    const float2 fw = fcw_s[g];
                    float o0 = hv*fw.x, o1 = hv*fw.y;
                    o0 += dpp_get<0x111>(o0); o1 += dpp_get<0x111>(o1);
                    o0 += dpp_get<0x112>(o0); o1 += dpp_get<0x112>(o1);
                    o0 += dpp_get<0x114>(o0); o1 += dpp_get<0x114>(o1);
                    o0 += dpp_get<0x118>(o0); o1 += dpp_get<0x118>(o1);
                    o0 += dpp_get<0x142>(o0); o1 += dpp_get<0x142>(o1);
                    o0 += dpp_get<0x143>(o0); o1 += dpp_get<0x143>(o1);
                    if (lane == 63) OpHiN[10 + wave] = make_float2(o0, o1);
                }
            }
        }

        // ---- finalize out[t-1] into out_s (LDS only; no vmcnt at barrier) --
        if (t > 0 && tid == 0) {
            const int tp = t - 1;
            if (ap >= 1) {
                for (int k = 2; k <= 2*ap+1; ++k) OpHi[k] = OpHiN[k];
            }
            float o0 = fb0, o1 = fb1;
            #pragma unroll
            for (int w = 0; w < 8; ++w) { o0 += OpM0[tp&1][w].x; o1 += OpM0[tp&1][w].y; }
            #pragma unroll
            for (int k = 2; k < 16; ++k) { o0 += OpHi[k].x; o1 += OpHi[k].y; }
            out_s[2*tp]   = o0;
            out_s[2*tp+1] = o1;
        }

        __syncthreads();            // the ONE barrier per step
    }

    if (tid == 0) {                 // out[511]
        float o0 = fb0, o1 = fb1;
        #pragma unroll
        for (int w = 0; w < 8; ++w) { o0 += OpM0[1][w].x; o1 += OpM0[1][w].y; }
        #pragma unroll
        for (int k = 2; k < 16; ++k) { o0 += OpHi[k].x; o1 += OpHi[k].y; }
        out_s[2*(Tsz-1)]   = o0;
        out_s[2*(Tsz-1)+1] = o1;
    }
    __syncthreads();
    for (int i = tid; i < Tsz*2; i += NT) outb[i] = out_s[i];
}

// ---------------------------------------------------------------------------
extern "C" void kernel_launch(void* const* d_in, const int* in_sizes, int n_in,
                              void* d_out, int out_size, void* d_ws, size_t ws_size,
                              hipStream_t stream) {
    const float* x     = (const float*)d_in[0];
    const float* W_ih  = (const float*)d_in[1];
    const float* W_hh  = (const float*)d_in[2];
    const float* fc_w  = (const float*)d_in[3];
    const float* fc_b  = (const float*)d_in[4];
    const float* enc_w = (const float*)d_in[5];
    float* outp = (float*)d_out;
    __half* WBr = (__half*)((char*)d_ws + 65536);        // 35*16384*2 B

    retile_whh<<<35, 256, 0, stream>>>(W_hh, WBr);
    cwrnn_kernel<<<Bsz, NT, 0, stream>>>(x, W_ih, fc_w, fc_b, enc_w, W_hh, WBr, outp);
}

// Round 13
// 886.880 us; speedup vs baseline: 1.7796x; 1.0436x over previous
//
#include <hip/hip_runtime.h>
#include <hip/hip_fp16.h>
#include <math.h>

#define Bsz 128
#define Tsz 512
#define Hsz 1024
#define MS  128
#define NT  512

// ws layout: [64KB, +1.09MB) WBr: fp16 pairs p=1..35, TID-INTERLEAVED (R7):
//   per pair, half offset o = k*4096 + tid*8 + e  (k=0..3, tid=0..511, e=0..7)
//   holds W(r,c)[tid>>2][(tid&3)*32 + (((k+(tid&3))&3)<<3) + e]
// -> LDS copies & reads: 64 consecutive 16B lanes per instr, 0 bank conflicts.
// -> global streams: 1KB contiguous per wave instruction, perfect coalescing.
// pair index p = c*(c+1)/2 + r  (block (r,c), r<=c)

// ---------------------------------------------------------------------------
__global__ __launch_bounds__(256)
void retile_whh(const float* __restrict__ W, __half* __restrict__ WBr) {
    const int p = blockIdx.x + 1;
    const int t = threadIdx.x;
    int c = 0;
    while ((c+1)*(c+2)/2 <= p) ++c;
    const int r = p - c*(c+1)/2;
    __half* wb = WBr + (size_t)(p-1) * MS * MS;
    for (int o = t; o < MS*MS; o += 256) {
        const int k  = o >> 12;
        const int tt = (o >> 3) & 511;
        const int e  = o & 7;
        const int row = tt >> 2, jq = tt & 3;
        const int col = jq*32 + (((k + jq) & 3) << 3) + e;
        wb[o] = __float2half(W[(size_t)(r*MS+row)*Hsz + c*MS + col]);
    }
}

__device__ __forceinline__ float fast_tanh(float x) {
    const float e = __expf(2.0f * x);
    return 1.0f - 2.0f * __builtin_amdgcn_rcpf(e + 1.0f);
}

template <int CTRL>
__device__ __forceinline__ float dpp_get(float v) {
    union { float f; int i; } u, o;
    u.f = v;
    o.i = __builtin_amdgcn_update_dpp(0, u.i, CTRL, 0xf, 0xf, true);
    return o.f;
}

// packed fp32 dual-FMA (VOP3P): acc.xy += a.xy * b.xy
__device__ __forceinline__ void pk_fma(float2& acc, float2 a, float2 b) {
    asm("v_pk_fma_f32 %0, %1, %2, %0" : "+v"(acc) : "v"(a), "v"(b));
}
// mixed-precision FMA (VOP3P): acc += f32(w.f16_lo/hi) * h  — the f16->f32
// promote happens inside the FMA (numerically == cvt+fma), no v_cvt issue.
__device__ __forceinline__ void fma_mix_lo(float& acc, int w, float h) {
    asm("v_fma_mix_f32 %0, %1, %2, %0 op_sel:[0,0,0] op_sel_hi:[1,0,0]"
        : "+v"(acc) : "v"(w), "v"(h));
}
__device__ __forceinline__ void fma_mix_hi(float& acc, int w, float h) {
    asm("v_fma_mix_f32 %0, %1, %2, %0 op_sel:[1,0,0] op_sel_hi:[1,0,0]"
        : "+v"(acc) : "v"(w), "v"(h));
}

union H4 { short4 s4; int i2[2]; };
union F4 { float4 v; float2 h[2]; };

// ---------------------------------------------------------------------------
// Persistent Clockwork RNN, grid=128, block=512 (8 waves). ONE barrier/step.
// HARD CONSTRAINT (R3/4/5/8/11/12): 512 threads -> 128-VGPR budget; live set
// must stay <=128 or scratch spills (WRITE_SIZE is the tell).
//
// R10 base (886us; VGPR 124, conflicts 0, WRITE 512KB) + ONE change:
// fp16 pair matvecs use v_fma_mix_f32 (f16 operand consumed directly by the
// fp32 FMA) -> 32 mix ops per 128-wide pair slice instead of 16 pk_fma +
// 32 v_cvt_f32_f16 (-33% issue on every fp16 matvec path; conversions were
// 2/3 of the odd-region matvec issue at VALUBusy~51% on active CUs).
// (R9 lesson: h stays fp32 everywhere; weights fp16 are fine.)
//
// Col 0 feeds only module 0: diagonal W00*h0 inline in quad layout
// (4 threads/row); off-diagonals are register quarter-partials R1..R7
// refreshed in the odd region after col c updates. r>=1 pair sums -> Sp2s
// (>=2-step slack). Weight homes: W00 fp32 regs; (0,1),(0,2) fp16 regs;
// (1,1),(1,2),(2,2) fp16 in WL LDS; c>=3 streamed fp16 from L2 (62 steps).
// ---------------------------------------------------------------------------
__global__ __launch_bounds__(NT)
void cwrnn_kernel(const float* __restrict__ x,      // [B, T+1, 2, 1]
                  const float* __restrict__ W_ih,   // [H, 2]
                  const float* __restrict__ fc_w,   // [2, H]
                  const float* __restrict__ fc_b,   // [2]
                  const float* __restrict__ enc_w,  // [H, 2]
                  const float* __restrict__ Whh,    // [H, H] fp32 originals
                  const __half* __restrict__ WBr,   // fp16 pairs, interleaved
                  float* __restrict__ out)          // [B, T, 2]
{
    __shared__ __half  WL[3*MS*MS];     // (1,1),(1,2),(2,2): 96 KB, interleaved
    __shared__ float   Sp2s[36][MS];    // full row-sums, pairs r>=1 only
    __shared__ float   h_s[Hsz];        // cols 1..7 (col 0 lives in H0)
    __shared__ float   H0[2][MS];       // module-0 state, ping-pong
    __shared__ float2  x_s[Tsz+1];
    __shared__ float2  wih_s[Hsz];
    __shared__ float2  fcw_s[Hsz];
    __shared__ float2  OpM0[2][8];      // module-0 fc partials (dbuf)
    __shared__ float2  OpHi[16];        // promoted hi-module fc partials
    __shared__ float2  OpHiN[16];       // staging (written at even regions)
    __shared__ float   out_s[Tsz*2];    // staged outputs (bulk store at end)

    const int tid   = threadIdx.x;
    const int lane  = tid & 63;
    const int wave  = tid >> 6;
    const int b     = blockIdx.x;
    const int row00 = tid >> 2;
    const int jc    = tid & 3;

    const float2* xb = (const float2*)(x + (size_t)b*(Tsz+1)*2);
    float* outb = out + (size_t)b*Tsz*2;

    for (int i = tid; i < Tsz+1; i += NT) x_s[i] = xb[i];
    for (int i = tid; i < Hsz; i += NT) wih_s[i] = ((const float2*)W_ih)[i];
    for (int i = tid; i < Hsz; i += NT) fcw_s[i] = make_float2(fc_w[i], fc_w[Hsz+i]);
    // WL staging: pairs p=2 ((1,1)), p=4 ((1,2)), p=5 ((2,2)); linear int4 copy
    {
        const int PSEL[3] = {2, 4, 5};
        for (int i = tid; i < 3*MS*MS/8; i += NT) {
            const int pi = i >> 11, rem = i & 2047;
            ((int4*)WL)[i] =
                ((const int4*)(WBr + (size_t)(PSEL[pi]-1)*MS*MS))[rem];
        }
    }
    if (tid < 16) { OpHi[tid] = make_float2(0.f,0.f); OpHiN[tid] = make_float2(0.f,0.f); }
    const float fb0 = fc_b[0], fb1 = fc_b[1];

    // W00 fp32 register cache, rotated chunk order (matches hq layout)
    F4 w00[8];
    #pragma unroll
    for (int u = 0; u < 8; ++u) {
        const int uu = (u + 2*jc) & 7;
        w00[u].v = *(const float4*)(Whh + (size_t)row00*Hsz + jc*32 + uu*4);
    }
    // fp16 register pairs (0,1)=p1, (0,2)=p3 from interleaved WBr
    short4 w01[8], w02[8];
    #pragma unroll
    for (int k = 0; k < 4; ++k) {
        *(int4*)(&w01[2*k]) = *(const int4*)(WBr + (size_t)0*MS*MS + k*4096 + tid*8);
        *(int4*)(&w02[2*k]) = *(const int4*)(WBr + (size_t)2*MS*MS + k*4096 + tid*8);
    }

    {   // h0 = x[:,0] @ enc_w.T
        const float2 x0 = xb[0];
        for (int i = tid; i < Hsz; i += NT) {
            const float2 ew = ((const float2*)enc_w)[i];
            const float v = x0.x*ew.x + x0.y*ew.y;
            h_s[i] = v;
            if (i < MS) H0[0][i] = v;
        }
    }
    __syncthreads();

    float R1=0.f,R2=0.f,R3=0.f,R4=0.f,R5=0.f,R6=0.f,R7=0.f;

    auto load_hq = [&](int c, F4* hq) {
        #pragma unroll
        for (int u = 0; u < 8; ++u) {
            const int uu = (u + 2*jc) & 7;
            hq[u].v = *(const float4*)(h_s + c*MS + jc*32 + uu*4);
        }
    };
    // 128-wide fp16 pair slice: 32 v_fma_mix_f32, 4 independent 8-deep chains
    auto pair_acc16 = [&](const short4* w, const F4* hq) -> float {
        float a0=0.f, a1=0.f, a2=0.f, a3=0.f;
        #pragma unroll
        for (int u = 0; u < 8; ++u) {
            H4 ww; ww.s4 = w[u];
            fma_mix_lo(a0, ww.i2[0], hq[u].v.x);
            fma_mix_hi(a1, ww.i2[0], hq[u].v.y);
            fma_mix_lo(a2, ww.i2[1], hq[u].v.z);
            fma_mix_hi(a3, ww.i2[1], hq[u].v.w);
        }
        return (a0 + a1) + (a2 + a3);
    };
    // conflict-free LDS pair read: 4 x ds_read_b128, lanes consecutive 16B
    auto wl_read = [&](int pi, short4* w) {
        const __half* base = WL + (size_t)pi*MS*MS + tid*8;
        #pragma unroll
        for (int k = 0; k < 4; ++k)
            *(int4*)(&w[2*k]) = *(const int4*)(base + k*4096);
    };
    // coalesced global pair read: 4 x dwordx4, 1KB contiguous per wave instr
    auto wg_load = [&](int p, short4* w) {
        const __half* base = WBr + (size_t)(p-1)*MS*MS + tid*8;
        #pragma unroll
        for (int k = 0; k < 4; ++k)
            *(int4*)(&w[2*k]) = *(const int4*)(base + k*4096);
    };

    // Refresh contributions of cols 1..ashad:
    //  r=0 -> register quarter-partials Rc; r>=1 -> quad-reduced Sp2s
    auto do_cols = [&](int ashad) {
        F4 hq[8];
        short4 wA[8], wB[8];
        if (ashad >= 3) wg_load(6, wA);          // prefetch (0,3) early
        load_hq(1, hq);
        wl_read(0, wB);                          // (1,1)
        R1 = pair_acc16(w01, hq);
        { float aa = pair_acc16(wB, hq);
          aa += dpp_get<0xB1>(aa); aa += dpp_get<0x4E>(aa);
          if (jc == 0) Sp2s[2][row00] = aa; }            // (1,1)
        if (ashad >= 2) {
            load_hq(2, hq);
            R2 = pair_acc16(w02, hq);
            wl_read(1, wB);
            { float aa = pair_acc16(wB, hq);
              aa += dpp_get<0xB1>(aa); aa += dpp_get<0x4E>(aa);
              if (jc == 0) Sp2s[4][row00] = aa; }        // (1,2)
            wl_read(2, wB);
            { float aa = pair_acc16(wB, hq);
              aa += dpp_get<0xB1>(aa); aa += dpp_get<0x4E>(aa);
              if (jc == 0) Sp2s[5][row00] = aa; }        // (2,2)
        }
        if (ashad >= 3) {
            // streamed pipeline: (0,3),(1,3)...(ashad,ashad), depth-2 prefetch
            load_hq(3, hq);
            int cc = 3, rr = 0;
            while (true) {
                int rn = rr + 1, cn = cc;
                if (rn > cn) { cn += 1; rn = 0; }
                const bool hn = (cn <= ashad);
                if (hn) wg_load(cn*(cn+1)/2 + rn, wB);
                float aa = pair_acc16(wA, hq);
                if (rr == 0) {
                    switch (cc) {
                        case 3: R3 = aa; break;
                        case 4: R4 = aa; break;
                        case 5: R5 = aa; break;
                        case 6: R6 = aa; break;
                        default: R7 = aa; break;
                    }
                } else {
                    aa += dpp_get<0xB1>(aa); aa += dpp_get<0x4E>(aa);
                    if (jc == 0) Sp2s[cc*(cc+1)/2 + rr][row00] = aa;
                }
                if (!hn) break;
                if (cn != cc) load_hq(cn, hq);
                cc = cn; rr = rn;
                #pragma unroll
                for (int u = 0; u < 8; ++u) wA[u] = wB[u];
            }
        }
    };

    do_cols(7);                 // init Sp2s + R1..R7 from encoder state
    __syncthreads();

    for (int t = 0; t < Tsz; ++t) {
        const int A  = (t == 0) ? 7 : ((t & 1) ? 0 : min(__ffs(t)-1, 7));
        const int ap = (t & 1) ? ((t == 1) ? 7 : min(__ffs(t-1)-1, 7)) : 0;
        const float2 xt = x_s[t+1];

        // ---- deferred refresh of cols active at t-1 (odd regions only) ----
        if (ap >= 1) do_cols(ap);

        // ---- module 0: inline diagonal + register off-diagonals ----
        {
            const float* h0r = H0[t & 1];
            float2 a0 = {0.f,0.f}, a1 = {0.f,0.f};
            #pragma unroll
            for (int u = 0; u < 8; ++u) {
                const int uu = (u + 2*jc) & 7;
                F4 hv; hv.v = *(const float4*)(h0r + jc*32 + uu*4);
                pk_fma(a0, w00[u].h[0], hv.h[0]);
                pk_fma(a1, w00[u].h[1], hv.h[1]);
            }
            float a = (a0.x + a0.y) + (a1.x + a1.y);
            a += ((R1+R2)+(R3+R4)) + ((R5+R6)+R7);
            a += dpp_get<0xB1>(a); a += dpp_get<0x4E>(a);   // quad reduce
            const float2 wih0 = wih_s[row00];
            const float hv0 = fast_tanh(a + xt.x*wih0.x + xt.y*wih0.y);
            if (jc == 0) H0[(t+1)&1][row00] = hv0;
            const float2 fw0 = fcw_s[row00];
            float o0 = (jc == 0) ? hv0*fw0.x : 0.f;
            float o1 = (jc == 0) ? hv0*fw0.y : 0.f;
            o0 += dpp_get<0x111>(o0); o1 += dpp_get<0x111>(o1);
            o0 += dpp_get<0x112>(o0); o1 += dpp_get<0x112>(o1);
            o0 += dpp_get<0x114>(o0); o1 += dpp_get<0x114>(o1);
            o0 += dpp_get<0x118>(o0); o1 += dpp_get<0x118>(o1);
            o0 += dpp_get<0x142>(o0); o1 += dpp_get<0x142>(o1);
            o0 += dpp_get<0x143>(o0); o1 += dpp_get<0x143>(o1);
            if (lane == 63) OpM0[t&1][wave] = make_float2(o0, o1);
        }

        // ---- modules 1..A: row updates from Sp2s (even & t==0) ----
        if (A >= 1) {
            const int nrows = (A+1)*MS;
            {
                const int g = MS + tid;
                if (g < nrows) {
                    const int r = g >> 7, il = g & (MS-1);
                    float sc[8];
                    #pragma unroll
                    for (int c = 1; c < 8; ++c)
                        sc[c] = Sp2s[c*(c+1)/2 + ((c < r) ? c : r)][il];
                    const float2 wih2 = wih_s[g];
                    float pre = xt.x*wih2.x + xt.y*wih2.y;
                    #pragma unroll
                    for (int c = 1; c < 8; ++c) pre += (c >= r) ? sc[c] : 0.f;
                    const float hv = fast_tanh(pre);
                    h_s[g] = hv;
                    const float2 fw = fcw_s[g];
                    float o0 = hv*fw.x, o1 = hv*fw.y;
                    o0 += dpp_get<0x111>(o0); o1 += dpp_get<0x111>(o1);
                    o0 += dpp_get<0x112>(o0); o1 += dpp_get<0x112>(o1);
                    o0 += dpp_get<0x114>(o0); o1 += dpp_get<0x114>(o1);
                    o0 += dpp_get<0x118>(o0); o1 += dpp_get<0x118>(o1);
                    o0 += dpp_get<0x142>(o0); o1 += dpp_get<0x142>(o1);
                    o0 += dpp_get<0x143>(o0); o1 += dpp_get<0x143>(o1);
                    if (lane == 63) OpHiN[2 + wave] = make_float2(o0, o1);
                }
            }
            {
                const int g = 5*MS + tid;
                if (g < nrows) {
                    const int r = g >> 7, il = g & (MS-1);
                    float sc[8];
                    #pragma unroll
                    for (int c = 1; c < 8; ++c)
                        sc[c] = Sp2s[c*(c+1)/2 + ((c < r) ? c : r)][il];
                    const float2 wih2 = wih_s[g];
                    float pre = xt.x*wih2.x + xt.y*wih2.y;
                    #pragma unroll
                    for (int c = 1; c < 8; ++c) pre += (c >= r) ? sc[c] : 0.f;
                    const float hv = fast_tanh(pre);
                    h_s[g] = hv;
                    const float2 fw = fcw_s[g];
                    float o0 = hv*fw.x, o1 = hv*fw.y;
                    o0 += dpp_get<0x111>(o0); o1 += dpp_get<0x111>(o1);
                    o0 += dpp_get<0x112>(o0); o1 += dpp_get<0x112>(o1);
                    o0 += dpp_get<0x114>(o0); o1 += dpp_get<0x114>(o1);
                    o0 += dpp_get<0x118>(o0); o1 += dpp_get<0x118>(o1);
                    o0 += dpp_get<0x142>(o0); o1 += dpp_get<0x142>(o1);
                    o0 += dpp_get<0x143>(o0); o1 += dpp_get<0x143>(o1);
                    if (lane == 63) OpHiN[10 + wave] = make_float2(o0, o1);
                }
            }
        }

        // ---- finalize out[t-1] into out_s (LDS only; no vmcnt at barrier) --
        if (t > 0 && tid == 0) {
            const int tp = t - 1;
            if (ap >= 1) {
                for (int k = 2; k <= 2*ap+1; ++k) OpHi[k] = OpHiN[k];
            }
            float o0 = fb0, o1 = fb1;
            #pragma unroll
            for (int w = 0; w < 8; ++w) { o0 += OpM0[tp&1][w].x; o1 += OpM0[tp&1][w].y; }
            #pragma unroll
            for (int k = 2; k < 16; ++k) { o0 += OpHi[k].x; o1 += OpHi[k].y; }
            out_s[2*tp]   = o0;
            out_s[2*tp+1] = o1;
        }

        __syncthreads();            // the ONE barrier per step
    }

    if (tid == 0) {                 // out[511]
        float o0 = fb0, o1 = fb1;
        #pragma unroll
        for (int w = 0; w < 8; ++w) { o0 += OpM0[1][w].x; o1 += OpM0[1][w].y; }
        #pragma unroll
        for (int k = 2; k < 16; ++k) { o0 += OpHi[k].x; o1 += OpHi[k].y; }
        out_s[2*(Tsz-1)]   = o0;
        out_s[2*(Tsz-1)+1] = o1;
    }
    __syncthreads();
    for (int i = tid; i < Tsz*2; i += NT) outb[i] = out_s[i];
}

// ---------------------------------------------------------------------------
extern "C" void kernel_launch(void* const* d_in, const int* in_sizes, int n_in,
                              void* d_out, int out_size, void* d_ws, size_t ws_size,
                              hipStream_t stream) {
    const float* x     = (const float*)d_in[0];
    const float* W_ih  = (const float*)d_in[1];
    const float* W_hh  = (const float*)d_in[2];
    const float* fc_w  = (const float*)d_in[3];
    const float* fc_b  = (const float*)d_in[4];
    const float* enc_w = (const float*)d_in[5];
    float* outp = (float*)d_out;
    __half* WBr = (__half*)((char*)d_ws + 65536);        // 35*16384*2 B

    retile_whh<<<35, 256, 0, stream>>>(W_hh, WBr);
    cwrnn_kernel<<<Bsz, NT, 0, stream>>>(x, W_ih, fc_w, fc_b, enc_w, W_hh, WBr, outp);
}